// Round 5
// baseline (180.786 us; speedup 1.0000x reference)
//
#include <hip/hip_runtime.h>
#include <stdint.h>

typedef unsigned short u16;
typedef short bf16x8 __attribute__((ext_vector_type(8)));
typedef float f32x4 __attribute__((ext_vector_type(4)));

#define S_ 2048
#define HID_ 1024
#define H_ 16
#define D_ 64

#define LOG2E 1.4426950408889634f
#define SCALE_LOG2 0.18033688011112042f   /* 0.125 * log2(e) */
#define MAXC_LOG2 11.541560327111707f     /* 8 * log2(e) */

__device__ __forceinline__ u16 f2bf(float f) {
  uint32_t x = __builtin_bit_cast(uint32_t, f);
  uint32_t r = (x + 0x7fffu + ((x >> 16) & 1u)) >> 16;
  return (u16)r;
}
__device__ __forceinline__ uint32_t packbf2(float a, float b) {
  return (uint32_t)f2bf(a) | ((uint32_t)f2bf(b) << 16);
}
// truncating pack: low16 = bf16(a), high16 = bf16(b), one v_perm_b32
__device__ __forceinline__ uint32_t permpack(float a, float b) {
  return __builtin_amdgcn_perm(__builtin_bit_cast(uint32_t, b),
                               __builtin_bit_cast(uint32_t, a), 0x07060302u);
}

__device__ __forceinline__ void gl2lds16(const void* g, void* l) {
  __builtin_amdgcn_global_load_lds(
      (const __attribute__((address_space(1))) unsigned int*)g,
      (__attribute__((address_space(3))) unsigned int*)l, 16, 0, 0);
}

// ------------- prep: converts + RoPE tables + mask2, one kernel -------------
#define NX_ (1 << 20)
#define NW_ (1 << 18)
#define NROPE_ 65536
__global__ void prep_kernel(const float* __restrict__ X, const float* __restrict__ Wq,
                            const float* __restrict__ Wk, const float* __restrict__ Wv,
                            const float* __restrict__ mask, u16* __restrict__ Xb,
                            u16* __restrict__ Wqb, u16* __restrict__ Wkb,
                            u16* __restrict__ Wvb, float* __restrict__ cos_t,
                            float* __restrict__ sin_t, float* __restrict__ mask2) {
  int i = blockIdx.x * 256 + threadIdx.x;
  if (i < NX_ + 3 * NW_) {
    const float* src;
    u16* dst;
    int off;
    if (i < NX_) {
      src = X; dst = Xb; off = i;
    } else if (i < NX_ + NW_) {
      src = Wq; dst = Wqb; off = i - NX_;
    } else if (i < NX_ + 2 * NW_) {
      src = Wk; dst = Wkb; off = i - NX_ - NW_;
    } else {
      src = Wv; dst = Wvb; off = i - NX_ - 2 * NW_;
    }
    float4 v = ((const float4*)src)[off];
    uint2 packed;
    packed.x = packbf2(v.x, v.y);
    packed.y = packbf2(v.z, v.w);
    ((uint2*)dst)[off] = packed;
  } else if (i < NX_ + 3 * NW_ + NROPE_) {
    int t = i - (NX_ + 3 * NW_);  // 65536 = 2048*32
    int s = t >> 5, j = t & 31;
    float invf = powf(10000.0f, -(float)j * (1.0f / 32.0f));
    float ang = (float)s * invf;
    cos_t[t] = cosf(ang);
    sin_t[t] = sinf(ang);
  } else {
    int t = i - (NX_ + 3 * NW_ + NROPE_);  // 4096 = 2*2048
    mask2[t] = fmaf(mask[t], LOG2E, -MAXC_LOG2);
  }
}

// ---------------- QKV GEMM (R0/R1 proven): X+W dbuf in LDS, 1 barrier/iter ----------------
// C = X(4096x1024) * W^T. 128x128 tile, BK=64, 4 waves 2x2.
// grid.x in [0,24): which = x>>3 (0:Q 1:K 2:V), nbase = (x&7)*128.
// which<2: SWAPPED mfma operands (C regs run along d) + fused RoPE.
__global__ __launch_bounds__(256) void qkv_gemm_kernel(
    const u16* __restrict__ X, const u16* __restrict__ Wq, const u16* __restrict__ Wk,
    const u16* __restrict__ Wv, const float* __restrict__ cos_t,
    const float* __restrict__ sin_t, u16* __restrict__ Q, u16* __restrict__ K,
    u16* __restrict__ Vt) {
  __shared__ char smem[65536];  // As[2] @ 0/16K, Bs[2] @ 32K/48K
  int tid = threadIdx.x;
  int lane = tid & 63, wave = tid >> 6;
  int wm = wave >> 1, wn = wave & 1;
  int quad = lane >> 4, l16 = lane & 15;
  int which = blockIdx.x >> 3;
  int nbase = (blockIdx.x & 7) * 128;
  int mbase = blockIdx.y * 128;
  const u16* W = (which == 0) ? Wq : (which == 1) ? Wk : Wv;

  // stage tile 0 into buffer 0
#pragma unroll
  for (int it = 0; it < 4; ++it) {
    int i = it * 256 + tid;
    int r = i >> 3, gs = i & 7, gsrc = gs ^ (r & 7);
    gl2lds16(X + (size_t)(mbase + r) * HID_ + gsrc * 8, smem + i * 16);
    gl2lds16(W + (size_t)(nbase + r) * HID_ + gsrc * 8, smem + 32768 + i * 16);
  }

  f32x4 acc[4][4] = {};

  for (int kk = 0; kk < 16; ++kk) {
    char* As = smem + (kk & 1) * 16384;
    char* Bs = smem + 32768 + (kk & 1) * 16384;
    __syncthreads();  // staging of current buffer complete

    if (kk < 15) {  // prefetch next tile into other buffer
      int k0n = (kk + 1) * 64;
      char* An = smem + ((kk + 1) & 1) * 16384;
      char* Bn = smem + 32768 + ((kk + 1) & 1) * 16384;
#pragma unroll
      for (int it = 0; it < 4; ++it) {
        int i = it * 256 + tid;
        int r = i >> 3, gs = i & 7, gsrc = gs ^ (r & 7);
        gl2lds16(X + (size_t)(mbase + r) * HID_ + k0n + gsrc * 8, An + i * 16);
        gl2lds16(W + (size_t)(nbase + r) * HID_ + k0n + gsrc * 8, Bn + i * 16);
      }
    }

#pragma unroll
    for (int kh = 0; kh < 2; ++kh) {
      bf16x8 afrag[4], bfrag[4];
#pragma unroll
      for (int i4 = 0; i4 < 4; ++i4) {
        int r = wm * 64 + i4 * 16 + l16;
        int L = r * 8 + ((kh * 4 + quad) ^ (r & 7));
        afrag[i4] = *(const bf16x8*)(As + L * 16);
      }
#pragma unroll
      for (int j4 = 0; j4 < 4; ++j4) {
        int r = wn * 64 + j4 * 16 + l16;
        int L = r * 8 + ((kh * 4 + quad) ^ (r & 7));
        bfrag[j4] = *(const bf16x8*)(Bs + L * 16);
      }
      if (which == 2) {
#pragma unroll
        for (int i4 = 0; i4 < 4; ++i4)
#pragma unroll
          for (int j4 = 0; j4 < 4; ++j4)
            acc[i4][j4] = __builtin_amdgcn_mfma_f32_16x16x32_bf16(afrag[i4], bfrag[j4],
                                                                  acc[i4][j4], 0, 0, 0);
      } else {
#pragma unroll
        for (int i4 = 0; i4 < 4; ++i4)
#pragma unroll
          for (int j4 = 0; j4 < 4; ++j4)
            acc[i4][j4] = __builtin_amdgcn_mfma_f32_16x16x32_bf16(bfrag[j4], afrag[i4],
                                                                  acc[i4][j4], 0, 0, 0);
      }
    }
  }

  if (which == 2) {
    // C tile: row = m-off = quad*4+reg, col = n-off = l16. 4 regs = 4 consecutive s.
#pragma unroll
    for (int i4 = 0; i4 < 4; ++i4)
#pragma unroll
      for (int j4 = 0; j4 < 4; ++j4) {
        int m = mbase + wm * 64 + i4 * 16 + quad * 4;
        int n = nbase + wn * 64 + j4 * 16 + l16;
        int b = m >> 11, s0 = m & 2047;
        int h = n >> 6, d = n & 63;
        uint2 pk;
        pk.x = packbf2(acc[i4][j4][0], acc[i4][j4][1]);
        pk.y = packbf2(acc[i4][j4][2], acc[i4][j4][3]);
        *(uint2*)(Vt + (((size_t)(b * H_ + h)) * D_ + d) * S_ + s0) = pk;
      }
  } else {
    // SWAPPED: row = n-off = quad*4+reg, col = m-off = l16. RoPE pair (d,d+32)=(j4,j4+2).
    u16* dst = (which == 0) ? Q : K;
#pragma unroll
    for (int i4 = 0; i4 < 4; ++i4)
#pragma unroll
      for (int j4 = 0; j4 < 2; ++j4) {
        int m = mbase + wm * 64 + i4 * 16 + l16;
        int n1 = nbase + wn * 64 + j4 * 16 + quad * 4;
        int b = m >> 11, s = m & 2047;
        int h = n1 >> 6, d1 = n1 & 63;  // d1 in [0,32), multiple of 4
        float4 c4 = *(const float4*)(cos_t + s * 32 + d1);
        float4 s4 = *(const float4*)(sin_t + s * 32 + d1);
        float y1[4], y2[4];
#pragma unroll
        for (int r = 0; r < 4; ++r) {
          float cr = ((const float*)&c4)[r], sr = ((const float*)&s4)[r];
          float x1 = acc[i4][j4][r], x2 = acc[i4][j4 + 2][r];
          y1[r] = x1 * cr - x2 * sr;
          y2[r] = x2 * cr + x1 * sr;
        }
        size_t base = ((size_t)(b * H_ + h) * S_ + s) * D_;
        uint2 p1, p2;
        p1.x = packbf2(y1[0], y1[1]);
        p1.y = packbf2(y1[2], y1[3]);
        p2.x = packbf2(y2[0], y2[1]);
        p2.y = packbf2(y2[2], y2[3]);
        *(uint2*)(dst + base + d1) = p1;
        *(uint2*)(dst + base + d1 + 32) = p2;
      }
  }
}

// ---------- flash helpers ----------
// PV step: P fragments come from REGISTERS (pp), V frags from LDS (read once,
// reused across both q-blocks).
__device__ __forceinline__ void pv_step(const bf16x8 (*pp)[2], const char* Vp, int quad,
                                        int l16, const bf16x8& ones, f32x4 (*o)[4],
                                        f32x4* lacc) {
  lacc[0] = __builtin_amdgcn_mfma_f32_16x16x32_bf16(pp[0][0], ones, lacc[0], 0, 0, 0);
  lacc[0] = __builtin_amdgcn_mfma_f32_16x16x32_bf16(pp[0][1], ones, lacc[0], 0, 0, 0);
  lacc[1] = __builtin_amdgcn_mfma_f32_16x16x32_bf16(pp[1][0], ones, lacc[1], 0, 0, 0);
  lacc[1] = __builtin_amdgcn_mfma_f32_16x16x32_bf16(pp[1][1], ones, lacc[1], 0, 0, 0);
#pragma unroll
  for (int jd = 0; jd < 4; ++jd) {
    int r = jd * 16 + l16;
#pragma unroll
    for (int kh = 0; kh < 2; ++kh) {
      int L = r * 8 + ((kh * 4 + quad) ^ (r & 7));
      bf16x8 vf = *(const bf16x8*)(Vp + L * 16);
      o[0][jd] = __builtin_amdgcn_mfma_f32_16x16x32_bf16(pp[0][kh], vf, o[0][jd], 0, 0, 0);
      o[1][jd] = __builtin_amdgcn_mfma_f32_16x16x32_bf16(pp[1][kh], vf, o[1][jd], 0, 0, 0);
    }
  }
}

// S^T = K * Q^T : row=key (quad*4+reg), col=q (l16). kf read once, 2 q-blocks.
__device__ __forceinline__ void qk_step(const char* Ks, const bf16x8 (*qfrag)[2], int quad,
                                        int l16, f32x4 (*s)[4]) {
#pragma unroll
  for (int jt = 0; jt < 4; ++jt) {
    int r = jt * 16 + l16;
#pragma unroll
    for (int kh = 0; kh < 2; ++kh) {
      int L = r * 8 + ((kh * 4 + quad) ^ (r & 7));
      bf16x8 kf = *(const bf16x8*)(Ks + L * 16);
      s[0][jt] = __builtin_amdgcn_mfma_f32_16x16x32_bf16(kf, qfrag[0][kh], s[0][jt], 0, 0, 0);
      s[1][jt] = __builtin_amdgcn_mfma_f32_16x16x32_bf16(kf, qfrag[1][kh], s[1][jt], 0, 0, 0);
    }
  }
}

// fixed-max softmax (exp2 + truncating perm-pack), then IN-REGISTER q<->key
// transpose via permlane swaps (replaces the P LDS round-trip).
__device__ __forceinline__ void softmax_pack(const f32x4 (*s)[4], const float4* mv,
                                             bf16x8 (*pp)[2]) {
#pragma unroll
  for (int qb = 0; qb < 2; ++qb) {
    uint32_t a[4][2];
#pragma unroll
    for (int jt = 0; jt < 4; ++jt) {
      float pf[4];
#pragma unroll
      for (int r = 0; r < 4; ++r) {
        float mvr = ((const float*)&mv[jt])[r];
        pf[r] = __builtin_amdgcn_exp2f(fmaf(s[qb][jt][r], SCALE_LOG2, mvr));
      }
      a[jt][0] = permpack(pf[0], pf[1]);
      a[jt][1] = permpack(pf[2], pf[3]);
    }
#pragma unroll
    for (int kh = 0; kh < 2; ++kh) {
      uint32_t tt[4];
#pragma unroll
      for (int i = 0; i < 2; ++i) {
        auto r1 = __builtin_amdgcn_permlane32_swap(a[2 * kh][i], a[2 * kh + 1][i],
                                                   false, false);
        auto r2 = __builtin_amdgcn_permlane16_swap(r1[0], r1[1], false, false);
        tt[i] = r2[0];      // T[kh][0+i]
        tt[2 + i] = r2[1];  // T[kh][2+i]
      }
      union { uint32_t u[4]; bf16x8 v; } cv;
      cv.u[0] = tt[0]; cv.u[1] = tt[1]; cv.u[2] = tt[2]; cv.u[3] = tt[3];
      pp[qb][kh] = cv.v;
    }
  }
}

// stage one 64-key tile: K -> Kd (64 keys x 64 d), V -> Vd (64 d x 64 keys).
// nb = absolute key offset (includes the KSPLIT half base).
__device__ __forceinline__ void stage_kv(const u16* Kbase, const u16* Vbase, char* Kd,
                                         char* Vd, int nb, int tid) {
#pragma unroll
  for (int hh = 0; hh < 2; ++hh) {
    int i = hh * 256 + tid;
    int r = i >> 3, gs = i & 7, gsrc = gs ^ (r & 7);
    gl2lds16(Kbase + (size_t)(nb + r) * D_ + gsrc * 8, Kd + i * 16);
    gl2lds16(Vbase + (size_t)r * S_ + nb + gsrc * 8, Vd + i * 16);
  }
}

// ---------------- Flash attention: KSPLIT=2, 256 threads, 4 waves x 32 q ----------------
// grid (16, 32, 2): blockIdx.z = key half (1024 keys = 16 tiles each).
// Fixed-max softmax => o/lacc are LINEAR over key tiles: half 0 writes unnormalized o
// to out, half 1 to po1, lacc partials to pl; combine_kernel sums + normalizes.
// LDS 40 KB: K double-buffered (lag-0 only), V triple-buffered (lag-1 PV) ->
// 4 blocks/CU, 1024 blocks = exactly one dispatch wave, 16 waves/CU (2x R4's TLP).
__global__ __launch_bounds__(256, 4) void flash_kernel(
    const u16* __restrict__ Q, const u16* __restrict__ K, const u16* __restrict__ Vt,
    const float* __restrict__ mask2, float* __restrict__ out0, float* __restrict__ po1,
    float* __restrict__ pl) {
  __shared__ char smem[40960];  // K: 2 bufs @ kb*8192; V: 3 bufs @ 16384 + vb*8192
  int tid = threadIdx.x, wave = tid >> 6;
  int lane = tid & 63;
  int quad = lane >> 4, l16 = lane & 15;
  int bh = blockIdx.y, b = bh >> 4, h = bh & 15;
  int half = blockIdx.z;
  int khbase = half << 10;  // 1024 keys per half
  int qbase = blockIdx.x * 128;
  int qw = qbase + wave * 32;
  const float* m2row = mask2 + b * S_;
  const u16* Kbase = K + (size_t)bh * S_ * D_;
  const u16* Vbase = Vt + (size_t)bh * D_ * S_;

  bf16x8 qfrag[2][2];
#pragma unroll
  for (int qb = 0; qb < 2; ++qb) {
    const u16* qp = Q + ((size_t)bh * S_ + qw + qb * 16 + l16) * D_ + quad * 8;
    qfrag[qb][0] = *(const bf16x8*)qp;
    qfrag[qb][1] = *(const bf16x8*)(qp + 32);
  }
  bf16x8 ones;
#pragma unroll
  for (int j = 0; j < 8; ++j) ones[j] = (short)0x3f80;  // bf16 1.0

  f32x4 o[2][4] = {};
  f32x4 lacc[2] = {};
  bf16x8 pp[2][2];  // P(t) fragments, consumed by PV in iter t+1

  // stage tile 0 into K buf 0 / V buf 0
  stage_kv(Kbase, Vbase, smem, smem + 16384, khbase, tid);
  // mask prefetch for t=0
  float4 mv[4];
#pragma unroll
  for (int jt = 0; jt < 4; ++jt)
    mv[jt] = *(const float4*)(m2row + khbase + jt * 16 + quad * 4);

  // ---- t = 0 (peeled: no PV) ----
  {
    __syncthreads();  // tile 0 staged
    stage_kv(Kbase, Vbase, smem + 8192, smem + 16384 + 8192, khbase + 64, tid);  // t=1
    f32x4 s[2][4] = {};
    __builtin_amdgcn_s_setprio(1);
    qk_step(smem, qfrag, quad, l16, s);
    __builtin_amdgcn_s_setprio(0);
    softmax_pack(s, mv, pp);
#pragma unroll
    for (int jt = 0; jt < 4; ++jt)
      mv[jt] = *(const float4*)(m2row + khbase + 64 + jt * 16 + quad * 4);
  }

  // ---- steady state t = 1..14 ----
  for (int t = 1; t <= 14; ++t) {
    __syncthreads();  // staging of tile t complete; K buf (t+1)&1, V buf (t+1)%3 free
    stage_kv(Kbase, Vbase, smem + ((t + 1) & 1) * 8192,
             smem + 16384 + ((t + 1) % 3) * 8192, khbase + (t + 1) * 64, tid);

    __builtin_amdgcn_s_setprio(1);
    // PV for tile t-1 from pp regs + V in buf (t-1)%3
    pv_step(pp, smem + 16384 + ((t - 1) % 3) * 8192, quad, l16, ones, o, lacc);

    f32x4 s[2][4] = {};
    qk_step(smem + (t & 1) * 8192, qfrag, quad, l16, s);
    __builtin_amdgcn_s_setprio(0);

    softmax_pack(s, mv, pp);  // overwrites pp with P(t) (PV above already consumed it)
#pragma unroll
    for (int jt = 0; jt < 4; ++jt)
      mv[jt] = *(const float4*)(m2row + khbase + (t + 1) * 64 + jt * 16 + quad * 4);
  }

  // ---- t = 15 (peeled: no stage, no mask prefetch) ----
  {
    __syncthreads();
    __builtin_amdgcn_s_setprio(1);
    pv_step(pp, smem + 16384 + 2 * 8192, quad, l16, ones, o, lacc);  // PV(14), 14%3=2
    f32x4 s[2][4] = {};
    qk_step(smem + 8192, qfrag, quad, l16, s);  // tile 15 in K buf 1
    __builtin_amdgcn_s_setprio(0);
    softmax_pack(s, mv, pp);
  }

  // drain: PV for tile 15 (V in buf 15%3 = 0)
  pv_step(pp, smem + 16384, quad, l16, ones, o, lacc);

  // epilogue: UNNORMALIZED partial o + row-sum partials (combine normalizes)
  float* dst = (half == 0) ? out0 : po1;
#pragma unroll
  for (int qb = 0; qb < 2; ++qb)
#pragma unroll
    for (int jd = 0; jd < 4; ++jd) {
#pragma unroll
      for (int r = 0; r < 4; ++r) {
        int d = jd * 16 + l16;
        int q = qw + qb * 16 + quad * 4 + r;
        dst[(((size_t)b * S_ + q) * H_ + h) * D_ + d] = o[qb][jd][r];
      }
    }
  if (l16 == 0) {  // lacc is l16-uniform (ones-matmul columns identical)
#pragma unroll
    for (int qb = 0; qb < 2; ++qb)
#pragma unroll
      for (int r = 0; r < 4; ++r) {
        int q = qw + qb * 16 + quad * 4 + r;
        pl[(half << 16) + bh * S_ + q] = lacc[qb][r];
      }
  }
}

// combine: out = (out + po1) / (pl0 + pl1), elementwise over [b][q][h][d].
__global__ __launch_bounds__(256) void combine_kernel(float* __restrict__ out,
                                                      const float* __restrict__ po1,
                                                      const float* __restrict__ pl) {
  int i = blockIdx.x * 256 + threadIdx.x;  // float4 index, 1,048,576 total
  int h = (i >> 4) & 15;
  int q = (i >> 8) & 2047;
  int b = i >> 19;
  int bhq = (b * 16 + h) * 2048 + q;
  float4 a = ((const float4*)out)[i];
  float4 c = ((const float4*)po1)[i];
  float inv = 1.0f / (pl[bhq] + pl[65536 + bhq]);
  float4 r;
  r.x = (a.x + c.x) * inv;
  r.y = (a.y + c.y) * inv;
  r.z = (a.z + c.z) * inv;
  r.w = (a.w + c.w) * inv;
  ((float4*)out)[i] = r;
}

extern "C" void kernel_launch(void* const* d_in, const int* in_sizes, int n_in,
                              void* d_out, int out_size, void* d_ws, size_t ws_size,
                              hipStream_t stream) {
  const float* hid = (const float*)d_in[0];
  const float* mask = (const float*)d_in[1];
  const float* Wq = (const float*)d_in[2];
  const float* Wk = (const float*)d_in[3];
  const float* Wv = (const float*)d_in[4];
  float* out = (float*)d_out;
  char* ws = (char*)d_ws;

  u16* Xbf = (u16*)ws;                              // 8 MB
  u16* Wqb = (u16*)(ws + (8u << 20));               // 2 MB
  u16* Wkb = (u16*)(ws + (10u << 20));              // 2 MB
  u16* Wvb = (u16*)(ws + (12u << 20));              // 2 MB
  u16* Qb = (u16*)(ws + (14u << 20));               // 8 MB (BH,S,D)
  u16* Kb = (u16*)(ws + (22u << 20));               // 8 MB (BH,S,D)
  u16* Vtb = (u16*)(ws + (30u << 20));              // 8 MB (BH,D,S)
  float* cos_t = (float*)(ws + (38u << 20));        // 256 KB
  float* sin_t = (float*)(ws + (38u << 20) + (256u << 10));
  float* mask2 = (float*)(ws + (38u << 20) + (512u << 10));  // 16 KB
  float* po1 = (float*)(ws + (40u << 20));          // 16 MB (half-1 partial o)
  float* pl = (float*)(ws + (56u << 20));           // 512 KB (lacc partials, 2 halves)

  prep_kernel<<<7440, 256, 0, stream>>>(hid, Wq, Wk, Wv, mask, Xbf, Wqb, Wkb, Wvb,
                                        cos_t, sin_t, mask2);
  qkv_gemm_kernel<<<dim3(24, 32), 256, 0, stream>>>(Xbf, Wqb, Wkb, Wvb, cos_t, sin_t,
                                                    Qb, Kb, Vtb);
  flash_kernel<<<dim3(16, 32, 2), 256, 0, stream>>>(Qb, Kb, Vtb, mask2, out, po1, pl);
  combine_kernel<<<4096, 256, 0, stream>>>(out, po1, pl);
}

// Round 6
// 160.235 us; speedup vs baseline: 1.1283x; 1.1283x over previous
//
#include <hip/hip_runtime.h>
#include <stdint.h>

typedef unsigned short u16;
typedef short bf16x8 __attribute__((ext_vector_type(8)));
typedef float f32x4 __attribute__((ext_vector_type(4)));

#define S_ 2048
#define HID_ 1024
#define H_ 16
#define D_ 64

#define LOG2E 1.4426950408889634f
#define SCALE_LOG2 0.18033688011112042f   /* 0.125 * log2(e) */
#define MAXC_LOG2 11.541560327111707f     /* 8 * log2(e) */

__device__ __forceinline__ u16 f2bf(float f) {
  uint32_t x = __builtin_bit_cast(uint32_t, f);
  uint32_t r = (x + 0x7fffu + ((x >> 16) & 1u)) >> 16;
  return (u16)r;
}
__device__ __forceinline__ uint32_t packbf2(float a, float b) {
  return (uint32_t)f2bf(a) | ((uint32_t)f2bf(b) << 16);
}
// truncating pack: low16 = bf16(a), high16 = bf16(b), one v_perm_b32
__device__ __forceinline__ uint32_t permpack(float a, float b) {
  return __builtin_amdgcn_perm(__builtin_bit_cast(uint32_t, b),
                               __builtin_bit_cast(uint32_t, a), 0x07060302u);
}

__device__ __forceinline__ void gl2lds16(const void* g, void* l) {
  __builtin_amdgcn_global_load_lds(
      (const __attribute__((address_space(1))) unsigned int*)g,
      (__attribute__((address_space(3))) unsigned int*)l, 16, 0, 0);
}

// ------------- prep: converts + RoPE tables + mask2, one kernel -------------
#define NX_ (1 << 20)
#define NW_ (1 << 18)
#define NROPE_ 65536
__global__ void prep_kernel(const float* __restrict__ X, const float* __restrict__ Wq,
                            const float* __restrict__ Wk, const float* __restrict__ Wv,
                            const float* __restrict__ mask, u16* __restrict__ Xb,
                            u16* __restrict__ Wqb, u16* __restrict__ Wkb,
                            u16* __restrict__ Wvb, float* __restrict__ cos_t,
                            float* __restrict__ sin_t, float* __restrict__ mask2) {
  int i = blockIdx.x * 256 + threadIdx.x;
  if (i < NX_ + 3 * NW_) {
    const float* src;
    u16* dst;
    int off;
    if (i < NX_) {
      src = X; dst = Xb; off = i;
    } else if (i < NX_ + NW_) {
      src = Wq; dst = Wqb; off = i - NX_;
    } else if (i < NX_ + 2 * NW_) {
      src = Wk; dst = Wkb; off = i - NX_ - NW_;
    } else {
      src = Wv; dst = Wvb; off = i - NX_ - 2 * NW_;
    }
    float4 v = ((const float4*)src)[off];
    uint2 packed;
    packed.x = packbf2(v.x, v.y);
    packed.y = packbf2(v.z, v.w);
    ((uint2*)dst)[off] = packed;
  } else if (i < NX_ + 3 * NW_ + NROPE_) {
    int t = i - (NX_ + 3 * NW_);  // 65536 = 2048*32
    int s = t >> 5, j = t & 31;
    float invf = powf(10000.0f, -(float)j * (1.0f / 32.0f));
    float ang = (float)s * invf;
    cos_t[t] = cosf(ang);
    sin_t[t] = sinf(ang);
  } else {
    int t = i - (NX_ + 3 * NW_ + NROPE_);  // 4096 = 2*2048
    mask2[t] = fmaf(mask[t], LOG2E, -MAXC_LOG2);
  }
}

// ---------------- Fused QKV GEMM: one block computes Q,K,V for a 128x128 tile ----------------
// grid (8, 32) = 256 blocks = 1/CU, ZERO dispatch tail (vs 768 @2/CU = 1.5 waves).
// 512 threads (8 waves: wm=wave>>2 in {0,1} x 64 m-rows; wn=wave&3).
// A (X tile) staged ONCE per K-step, shared by all 3 B matrices: 48 MFMA / 20 ds_read
// per wave per K-step (vs 32/16 split kernels), 1/3 the X global fetch.
// LDS 128 KB: buf p @ p*65536 { A @+0, Bq @+16K, Bk @+32K, Bv @+48K }, dbuf,
// stage-before-compute (proven R0 order), 1 barrier/K-step.
// Wave n-cols interleave 16-col groups {(wn&1)*16, +32} within head (wn>>1) so the
// RoPE pair (d1, d1+32) = (j2=0, j2=1) stays intra-wave.
__global__ __launch_bounds__(512, 2) void qkv_gemm_kernel(
    const u16* __restrict__ X, const u16* __restrict__ Wq, const u16* __restrict__ Wk,
    const u16* __restrict__ Wv, const float* __restrict__ cos_t,
    const float* __restrict__ sin_t, u16* __restrict__ Q, u16* __restrict__ K,
    u16* __restrict__ Vt) {
  __shared__ char smem[131072];
  int tid = threadIdx.x;
  int lane = tid & 63, wave = tid >> 6;
  int wm = wave >> 2, wn = wave & 3;
  int quad = lane >> 4, l16 = lane & 15;
  int nbase = blockIdx.x * 128;
  int mbase = blockIdx.y * 128;

  // ---- staging: 64 KB per K-step, 8 chunks/thread, sel = it>>1 compile-time ----
  // j in [0,1024): r = j>>3 (row), gs = j&7; inverse-swizzled GLOBAL source keeps
  // the proven read-side swizzle L = r*8 + ((kh*4+quad)^(r&7)).
#define STAGE_ALL(k0, buf)                                                        \
  {                                                                               \
    _Pragma("unroll") for (int it = 0; it < 8; ++it) {                            \
      int j = (it & 1) * 512 + tid;                                               \
      int r = j >> 3, gs = j & 7, gsrc = gs ^ (r & 7);                            \
      const u16* src; int rb;                                                     \
      if ((it >> 1) == 0)      { src = X;  rb = mbase + r; }                      \
      else if ((it >> 1) == 1) { src = Wq; rb = nbase + r; }                      \
      else if ((it >> 1) == 2) { src = Wk; rb = nbase + r; }                      \
      else                     { src = Wv; rb = nbase + r; }                      \
      gl2lds16(src + (size_t)rb * HID_ + (k0) + gsrc * 8,                         \
               (buf) + (it >> 1) * 16384 + j * 16);                               \
    }                                                                             \
  }

  STAGE_ALL(0, smem)  // tile 0 -> buf 0

  f32x4 acc[3][4][2] = {};  // [which][i4 m-block][j2 n-pair]

  for (int kk = 0; kk < 16; ++kk) {
    const char* buf = smem + (kk & 1) * 65536;
    __syncthreads();  // staging of tile kk complete

    if (kk < 15)  // stage tile kk+1 into other buffer (its reads finished pre-barrier)
      STAGE_ALL((kk + 1) * 64, smem + ((kk + 1) & 1) * 65536)

#pragma unroll
    for (int kh = 0; kh < 2; ++kh) {
      bf16x8 afrag[4];
#pragma unroll
      for (int i4 = 0; i4 < 4; ++i4) {
        int r = wm * 64 + i4 * 16 + l16;
        int L = r * 8 + ((kh * 4 + quad) ^ (r & 7));
        afrag[i4] = *(const bf16x8*)(buf + L * 16);
      }
#pragma unroll
      for (int w = 0; w < 3; ++w) {
        const char* Bs = buf + 16384 + w * 16384;
        bf16x8 bfrag[2];
#pragma unroll
        for (int j2 = 0; j2 < 2; ++j2) {
          int r = (wn >> 1) * 64 + (wn & 1) * 16 + j2 * 32 + l16;
          int L = r * 8 + ((kh * 4 + quad) ^ (r & 7));
          bfrag[j2] = *(const bf16x8*)(Bs + L * 16);
        }
        if (w == 2) {
#pragma unroll
          for (int i4 = 0; i4 < 4; ++i4)
#pragma unroll
            for (int j2 = 0; j2 < 2; ++j2)
              acc[2][i4][j2] = __builtin_amdgcn_mfma_f32_16x16x32_bf16(
                  afrag[i4], bfrag[j2], acc[2][i4][j2], 0, 0, 0);
        } else if (w == 1) {
#pragma unroll
          for (int i4 = 0; i4 < 4; ++i4)
#pragma unroll
            for (int j2 = 0; j2 < 2; ++j2)
              acc[1][i4][j2] = __builtin_amdgcn_mfma_f32_16x16x32_bf16(
                  bfrag[j2], afrag[i4], acc[1][i4][j2], 0, 0, 0);
        } else {
#pragma unroll
          for (int i4 = 0; i4 < 4; ++i4)
#pragma unroll
            for (int j2 = 0; j2 < 2; ++j2)
              acc[0][i4][j2] = __builtin_amdgcn_mfma_f32_16x16x32_bf16(
                  bfrag[j2], afrag[i4], acc[0][i4][j2], 0, 0, 0);
        }
      }
    }
  }
#undef STAGE_ALL

  // ---- V epilogue (w=2, non-swapped): C row = m (quad*4+reg), col = n (l16) ----
#pragma unroll
  for (int i4 = 0; i4 < 4; ++i4)
#pragma unroll
    for (int j2 = 0; j2 < 2; ++j2) {
      int m = mbase + wm * 64 + i4 * 16 + quad * 4;
      int n = nbase + (wn >> 1) * 64 + (wn & 1) * 16 + j2 * 32 + l16;
      int b = m >> 11, s0 = m & 2047;
      int h = n >> 6, d = n & 63;
      uint2 pk;
      pk.x = packbf2(acc[2][i4][j2][0], acc[2][i4][j2][1]);
      pk.y = packbf2(acc[2][i4][j2][2], acc[2][i4][j2][3]);
      *(uint2*)(Vt + (((size_t)(b * H_ + h)) * D_ + d) * S_ + s0) = pk;
    }

  // ---- Q/K epilogue (swapped): C row = n (quad*4+reg), col = m (l16); fused RoPE.
  // Pair (d1, d1+32) = (acc[w][i4][0], acc[w][i4][1]); d1 = (wn&1)*16 + quad*4.
#pragma unroll
  for (int w = 0; w < 2; ++w) {
    u16* dst = (w == 0) ? Q : K;
#pragma unroll
    for (int i4 = 0; i4 < 4; ++i4) {
      int m = mbase + wm * 64 + i4 * 16 + l16;
      int n1 = nbase + (wn >> 1) * 64 + (wn & 1) * 16 + quad * 4;
      int b = m >> 11, s = m & 2047;
      int h = n1 >> 6, d1 = n1 & 63;  // d1 in [0,32), multiple of 4
      float4 c4 = *(const float4*)(cos_t + s * 32 + d1);
      float4 s4 = *(const float4*)(sin_t + s * 32 + d1);
      float y1[4], y2[4];
#pragma unroll
      for (int r = 0; r < 4; ++r) {
        float cr = ((const float*)&c4)[r], sr = ((const float*)&s4)[r];
        float x1 = acc[w][i4][0][r], x2 = acc[w][i4][1][r];
        y1[r] = x1 * cr - x2 * sr;
        y2[r] = x2 * cr + x1 * sr;
      }
      size_t base = ((size_t)(b * H_ + h) * S_ + s) * D_;
      uint2 p1, p2;
      p1.x = packbf2(y1[0], y1[1]);
      p1.y = packbf2(y1[2], y1[3]);
      p2.x = packbf2(y2[0], y2[1]);
      p2.y = packbf2(y2[2], y2[3]);
      *(uint2*)(dst + base + d1) = p1;
      *(uint2*)(dst + base + d1 + 32) = p2;
    }
  }
}

// ---------- flash helpers (R4 proven) ----------
// PV step: P fragments come from REGISTERS (pp), V frags from LDS (read once,
// reused across both q-blocks).
__device__ __forceinline__ void pv_step(const bf16x8 (*pp)[2], const char* Vp, int quad,
                                        int l16, const bf16x8& ones, f32x4 (*o)[4],
                                        f32x4* lacc) {
  lacc[0] = __builtin_amdgcn_mfma_f32_16x16x32_bf16(pp[0][0], ones, lacc[0], 0, 0, 0);
  lacc[0] = __builtin_amdgcn_mfma_f32_16x16x32_bf16(pp[0][1], ones, lacc[0], 0, 0, 0);
  lacc[1] = __builtin_amdgcn_mfma_f32_16x16x32_bf16(pp[1][0], ones, lacc[1], 0, 0, 0);
  lacc[1] = __builtin_amdgcn_mfma_f32_16x16x32_bf16(pp[1][1], ones, lacc[1], 0, 0, 0);
#pragma unroll
  for (int jd = 0; jd < 4; ++jd) {
    int r = jd * 16 + l16;
#pragma unroll
    for (int kh = 0; kh < 2; ++kh) {
      int L = r * 8 + ((kh * 4 + quad) ^ (r & 7));
      bf16x8 vf = *(const bf16x8*)(Vp + L * 16);
      o[0][jd] = __builtin_amdgcn_mfma_f32_16x16x32_bf16(pp[0][kh], vf, o[0][jd], 0, 0, 0);
      o[1][jd] = __builtin_amdgcn_mfma_f32_16x16x32_bf16(pp[1][kh], vf, o[1][jd], 0, 0, 0);
    }
  }
}

// S^T = K * Q^T : row=key (quad*4+reg), col=q (l16). kf read once, 2 q-blocks.
__device__ __forceinline__ void qk_step(const char* Ks, const bf16x8 (*qfrag)[2], int quad,
                                        int l16, f32x4 (*s)[4]) {
#pragma unroll
  for (int jt = 0; jt < 4; ++jt) {
    int r = jt * 16 + l16;
#pragma unroll
    for (int kh = 0; kh < 2; ++kh) {
      int L = r * 8 + ((kh * 4 + quad) ^ (r & 7));
      bf16x8 kf = *(const bf16x8*)(Ks + L * 16);
      s[0][jt] = __builtin_amdgcn_mfma_f32_16x16x32_bf16(kf, qfrag[0][kh], s[0][jt], 0, 0, 0);
      s[1][jt] = __builtin_amdgcn_mfma_f32_16x16x32_bf16(kf, qfrag[1][kh], s[1][jt], 0, 0, 0);
    }
  }
}

// fixed-max softmax (exp2 + truncating perm-pack), then IN-REGISTER q<->key
// transpose via permlane swaps (replaces the P LDS round-trip).
__device__ __forceinline__ void softmax_pack(const f32x4 (*s)[4], const float4* mv,
                                             bf16x8 (*pp)[2]) {
#pragma unroll
  for (int qb = 0; qb < 2; ++qb) {
    uint32_t a[4][2];
#pragma unroll
    for (int jt = 0; jt < 4; ++jt) {
      float pf[4];
#pragma unroll
      for (int r = 0; r < 4; ++r) {
        float mvr = ((const float*)&mv[jt])[r];
        pf[r] = __builtin_amdgcn_exp2f(fmaf(s[qb][jt][r], SCALE_LOG2, mvr));
      }
      a[jt][0] = permpack(pf[0], pf[1]);
      a[jt][1] = permpack(pf[2], pf[3]);
    }
#pragma unroll
    for (int kh = 0; kh < 2; ++kh) {
      uint32_t tt[4];
#pragma unroll
      for (int i = 0; i < 2; ++i) {
        auto r1 = __builtin_amdgcn_permlane32_swap(a[2 * kh][i], a[2 * kh + 1][i],
                                                   false, false);
        auto r2 = __builtin_amdgcn_permlane16_swap(r1[0], r1[1], false, false);
        tt[i] = r2[0];      // T[kh][0+i]
        tt[2 + i] = r2[1];  // T[kh][2+i]
      }
      union { uint32_t u[4]; bf16x8 v; } cv;
      cv.u[0] = tt[0]; cv.u[1] = tt[1]; cv.u[2] = tt[2]; cv.u[3] = tt[3];
      pp[qb][kh] = cv.v;
    }
  }
}

__device__ __forceinline__ void stage_kv(const u16* Kbase, const u16* Vbase, char* Kn,
                                         int nb, int tid) {
#pragma unroll
  for (int half = 0; half < 2; ++half) {
    int i = half * 256 + tid;
    int r = i >> 3, gs = i & 7, gsrc = gs ^ (r & 7);
    gl2lds16(Kbase + (size_t)(nb + r) * D_ + gsrc * 8, Kn + i * 16);
    gl2lds16(Vbase + (size_t)r * S_ + nb + gsrc * 8, Kn + 8192 + i * 16);
  }
}

// ---------------- Flash attention (R4 proven): 256 threads, 4 waves x 32 q ----------------
// grid (16, 32), 2 blocks/CU. 64-key tiles, triple-buffered K/V (48 KB LDS),
// P entirely in registers (permlane transpose), 1 barrier/tile.
// Steady iter kt: stage kt+1; PV(kt-1) from pp regs; QK(kt); softmax+permlane -> pp.
__global__ __launch_bounds__(256, 2) void flash_kernel(
    const u16* __restrict__ Q, const u16* __restrict__ K, const u16* __restrict__ Vt,
    const float* __restrict__ mask2, float* __restrict__ out) {
  __shared__ char smem[49152];  // K/V: 3 bufs @ b*16384 (K@+0, V@+8192)
  int tid = threadIdx.x, wave = tid >> 6;
  int lane = tid & 63;
  int quad = lane >> 4, l16 = lane & 15;
  int bh = blockIdx.y, b = bh >> 4, h = bh & 15;
  int qbase = blockIdx.x * 128;
  int qw = qbase + wave * 32;
  const float* m2row = mask2 + b * S_;
  const u16* Kbase = K + (size_t)bh * S_ * D_;
  const u16* Vbase = Vt + (size_t)bh * D_ * S_;

  bf16x8 qfrag[2][2];
#pragma unroll
  for (int qb = 0; qb < 2; ++qb) {
    const u16* qp = Q + ((size_t)bh * S_ + qw + qb * 16 + l16) * D_ + quad * 8;
    qfrag[qb][0] = *(const bf16x8*)qp;
    qfrag[qb][1] = *(const bf16x8*)(qp + 32);
  }
  bf16x8 ones;
#pragma unroll
  for (int j = 0; j < 8; ++j) ones[j] = (short)0x3f80;  // bf16 1.0

  f32x4 o[2][4] = {};
  f32x4 lacc[2] = {};
  bf16x8 pp[2][2];  // P(kt) fragments, consumed by PV in iter kt+1

  // stage tile 0 into buffer 0
  stage_kv(Kbase, Vbase, smem, 0, tid);
  // mask prefetch for kt=0 (per-key, indexed by jt*16 + quad*4 + r)
  float4 mv[4];
#pragma unroll
  for (int jt = 0; jt < 4; ++jt) mv[jt] = *(const float4*)(m2row + jt * 16 + quad * 4);

  // ---- kt = 0 (peeled: no PV) ----
  {
    __syncthreads();  // tile 0 staged
    stage_kv(Kbase, Vbase, smem + 16384, 64, tid);  // tile 1 -> buf 1
    f32x4 s[2][4] = {};
    __builtin_amdgcn_s_setprio(1);
    qk_step(smem, qfrag, quad, l16, s);
    __builtin_amdgcn_s_setprio(0);
    softmax_pack(s, mv, pp);
#pragma unroll
    for (int jt = 0; jt < 4; ++jt)
      mv[jt] = *(const float4*)(m2row + 64 + jt * 16 + quad * 4);
  }

  // ---- steady state kt = 1..30 ----
  for (int kt = 1; kt <= 30; ++kt) {
    char* Ks = smem + (kt % 3) * 16384;
    __syncthreads();  // staging of tile kt complete; buf (kt+1)%3 free (PV(kt-2) done)
    stage_kv(Kbase, Vbase, smem + ((kt + 1) % 3) * 16384, (kt + 1) * 64, tid);

    __builtin_amdgcn_s_setprio(1);
    // PV for tile kt-1 from pp regs + V in buf (kt-1)%3
    const char* Vp = smem + ((kt - 1) % 3) * 16384 + 8192;
    pv_step(pp, Vp, quad, l16, ones, o, lacc);

    f32x4 s[2][4] = {};
    qk_step(Ks, qfrag, quad, l16, s);
    __builtin_amdgcn_s_setprio(0);

    softmax_pack(s, mv, pp);  // overwrites pp with P(kt) (PV above already consumed it)
#pragma unroll
    for (int jt = 0; jt < 4; ++jt)
      mv[jt] = *(const float4*)(m2row + (kt + 1) * 64 + jt * 16 + quad * 4);
  }

  // ---- kt = 31 (peeled: no stage, no mask prefetch) ----
  {
    __syncthreads();
    __builtin_amdgcn_s_setprio(1);
    pv_step(pp, smem + 0 * 16384 + 8192, quad, l16, ones, o, lacc);  // PV(30), buf 0
    f32x4 s[2][4] = {};
    qk_step(smem + 16384, qfrag, quad, l16, s);  // tile 31 in buf 1
    __builtin_amdgcn_s_setprio(0);
    softmax_pack(s, mv, pp);
  }

  // drain: PV for tile 31 (V in buf 31%3 = 1)
  pv_step(pp, smem + 16384 + 8192, quad, l16, ones, o, lacc);

  // epilogue: lacc[qb][r] holds the full row-sum for q = qw + qb*16 + quad*4 + r
  float inv[2][4];
#pragma unroll
  for (int qb = 0; qb < 2; ++qb)
#pragma unroll
    for (int r = 0; r < 4; ++r) inv[qb][r] = 1.0f / lacc[qb][r];
#pragma unroll
  for (int qb = 0; qb < 2; ++qb)
#pragma unroll
    for (int jd = 0; jd < 4; ++jd) {
#pragma unroll
      for (int r = 0; r < 4; ++r) {
        int d = jd * 16 + l16;
        int q = qw + qb * 16 + quad * 4 + r;
        out[(((size_t)b * S_ + q) * H_ + h) * D_ + d] = o[qb][jd][r] * inv[qb][r];
      }
    }
}

extern "C" void kernel_launch(void* const* d_in, const int* in_sizes, int n_in,
                              void* d_out, int out_size, void* d_ws, size_t ws_size,
                              hipStream_t stream) {
  const float* hid = (const float*)d_in[0];
  const float* mask = (const float*)d_in[1];
  const float* Wq = (const float*)d_in[2];
  const float* Wk = (const float*)d_in[3];
  const float* Wv = (const float*)d_in[4];
  float* out = (float*)d_out;
  char* ws = (char*)d_ws;

  u16* Xbf = (u16*)ws;                              // 8 MB
  u16* Wqb = (u16*)(ws + (8u << 20));               // 2 MB
  u16* Wkb = (u16*)(ws + (10u << 20));              // 2 MB
  u16* Wvb = (u16*)(ws + (12u << 20));              // 2 MB
  u16* Qb = (u16*)(ws + (14u << 20));               // 8 MB (BH,S,D)
  u16* Kb = (u16*)(ws + (22u << 20));               // 8 MB (BH,S,D)
  u16* Vtb = (u16*)(ws + (30u << 20));              // 8 MB (BH,D,S)
  float* cos_t = (float*)(ws + (38u << 20));        // 256 KB
  float* sin_t = (float*)(ws + (38u << 20) + (256u << 10));
  float* mask2 = (float*)(ws + (38u << 20) + (512u << 10));  // 16 KB

  prep_kernel<<<7440, 256, 0, stream>>>(hid, Wq, Wk, Wv, mask, Xbf, Wqb, Wkb, Wvb,
                                        cos_t, sin_t, mask2);
  qkv_gemm_kernel<<<dim3(8, 32), 512, 0, stream>>>(Xbf, Wqb, Wkb, Wvb, cos_t, sin_t,
                                                   Qb, Kb, Vtb);
  flash_kernel<<<dim3(16, 32), 256, 0, stream>>>(Qb, Kb, Vtb, mask2, out);
}